// Round 2
// baseline (1019.300 us; speedup 1.0000x reference)
//
#include <hip/hip_runtime.h>

// Problem constants (from reference)
#define Hh 256
#define Ww 256
#define Cc 32
#define NV 16
#define NN 4
#define NL 4
#define PLANE (Hh * Ww)   // 65536

// ---------------------------------------------------------------------------
// Kernel 1: transpose feats [V][C][H][W] -> tr [V][H*W][C] (channels-last).
// Tile = 32 channels x 64 pixels, staged through LDS; coalesced on both sides.
// ---------------------------------------------------------------------------
__global__ __launch_bounds__(256) void transpose_k(
    const float* __restrict__ feats, float* __restrict__ tr)
{
    __shared__ float lds[Cc][65];  // +1 pad -> (c+p) bank pattern, conflict-free
    const int v  = blockIdx.x >> 10;            // 1024 pixel-tiles per view
    const int p0 = (blockIdx.x & 1023) << 6;    // 64 pixels per tile
    const int t  = threadIdx.x;

    const float* fv = feats + (size_t)v * Cc * PLANE;
    #pragma unroll
    for (int i = 0; i < 8; ++i) {
        const int e = i * 256 + t;
        const int c = e >> 6, p = e & 63;
        lds[c][p] = fv[(size_t)c * PLANE + p0 + p];   // 256B contiguous per wave
    }
    __syncthreads();
    float* trv = tr + ((size_t)v * PLANE + p0) * Cc;
    #pragma unroll
    for (int i = 0; i < 8; ++i) {
        const int e = i * 256 + t;                    // e = p*32 + c
        const int p = e >> 5, c = e & 31;
        trv[e] = lds[c][p];                           // fully contiguous stores
    }
}

// ---------------------------------------------------------------------------
// Kernel 2: warp. One wave per (n,v,y) row; each thread owns 4 consecutive x.
// Winner layer per pixel, then 8 groups of 4 channels: float4 gather from
// channels-last tr (128B per pixel, fully used), 4x4 register transpose,
// float4 stores to [C,H,W]-layout output.
// ---------------------------------------------------------------------------
__global__ __launch_bounds__(256) void warp_v2(
    const float* __restrict__ tr,     // [V][HW][C]
    const int*   __restrict__ depth,  // [V][HW]
    const float* __restrict__ novel,  // [NN][2]
    const float* __restrict__ vpos,   // [NV][2]
    float*       __restrict__ out)    // [NN][NV][C][H][W]
{
    const int t  = threadIdx.x;
    const int r  = t >> 6;                       // row within block (0..3)
    const int xq = (t & 63) << 2;                // pixel quad base 0,4,..252
    const int y  = ((blockIdx.x & 63) << 2) + r;
    const int v  = (blockIdx.x >> 6) & (NV - 1);
    const int n  = blockIdx.x >> 10;

    const float dvx = vpos[2 * v]     - novel[2 * n];
    const float dvy = vpos[2 * v + 1] - novel[2 * n + 1];
    const float diop[NL] = {0.5f, 1.0f, 2.0f, 3.0f};
    int dxl[NL], dyl[NL];
    #pragma unroll
    for (int l = 0; l < NL; ++l) {
        dxl[l] = (int)rintf((dvx * diop[l]) * 128.0f);  // RNE, matches jnp.round
        dyl[l] = (int)rintf((dvy * diop[l]) * 128.0f);
    }

    const int*   dv  = depth + v * PLANE;
    const float* trv = tr + (size_t)v * PLANE * Cc;

    int srcpix[4];  // winning source pixel index, or -1
    #pragma unroll
    for (int j = 0; j < 4; ++j) {
        const int x = xq + j;
        int w = -1;
        #pragma unroll
        for (int l = NL - 1; l >= 0; --l) {
            const int sy = y - dyl[l];
            const int sx = x - dxl[l];
            if (w < 0 && sy >= 0 && sy < Hh && sx >= 0 && sx < Ww) {
                if (dv[sy * Ww + sx] == l) w = sy * Ww + sx;
            }
        }
        srcpix[j] = w;
    }

    float* ob = out + ((size_t)(n * NV + v) * Cc) * PLANE + (size_t)y * Ww + xq;

    #pragma unroll
    for (int g = 0; g < 8; ++g) {
        float4 f0 = make_float4(0.f, 0.f, 0.f, 0.f);
        float4 f1 = f0, f2 = f0, f3 = f0;
        if (srcpix[0] >= 0) f0 = *(const float4*)(trv + (size_t)srcpix[0] * Cc + g * 4);
        if (srcpix[1] >= 0) f1 = *(const float4*)(trv + (size_t)srcpix[1] * Cc + g * 4);
        if (srcpix[2] >= 0) f2 = *(const float4*)(trv + (size_t)srcpix[2] * Cc + g * 4);
        if (srcpix[3] >= 0) f3 = *(const float4*)(trv + (size_t)srcpix[3] * Cc + g * 4);
        // 4x4 register transpose: channel c across the 4 pixels -> one float4 store
        *(float4*)(ob + (size_t)(g * 4 + 0) * PLANE) = make_float4(f0.x, f1.x, f2.x, f3.x);
        *(float4*)(ob + (size_t)(g * 4 + 1) * PLANE) = make_float4(f0.y, f1.y, f2.y, f3.y);
        *(float4*)(ob + (size_t)(g * 4 + 2) * PLANE) = make_float4(f0.z, f1.z, f2.z, f3.z);
        *(float4*)(ob + (size_t)(g * 4 + 3) * PLANE) = make_float4(f0.w, f1.w, f2.w, f3.w);
    }
}

// ---------------------------------------------------------------------------
// Fallback (R0 kernel) if ws_size is too small for the channels-last copy.
// ---------------------------------------------------------------------------
__global__ __launch_bounds__(256) void warp_fallback(
    const float* __restrict__ feats, const int* __restrict__ depth,
    const float* __restrict__ novel, const float* __restrict__ vpos,
    float* __restrict__ out)
{
    const int x = threadIdx.x;
    const int y = blockIdx.x & (Hh - 1);
    const int v = (blockIdx.x >> 8) & (NV - 1);
    const int n = blockIdx.x >> 12;
    const float dvx = vpos[2 * v]     - novel[2 * n];
    const float dvy = vpos[2 * v + 1] - novel[2 * n + 1];
    const float diop[NL] = {0.5f, 1.0f, 2.0f, 3.0f};
    const int* dv = depth + v * PLANE;
    int winner = -1;
    #pragma unroll
    for (int l = NL - 1; l >= 0; --l) {
        const int dx = (int)rintf((dvx * diop[l]) * 128.0f);
        const int dy = (int)rintf((dvy * diop[l]) * 128.0f);
        const int sy = y - dy, sx = x - dx;
        if (winner < 0 && sy >= 0 && sy < Hh && sx >= 0 && sx < Ww)
            if (dv[sy * Ww + sx] == l) winner = sy * Ww + sx;
    }
    float* ob = out + ((size_t)(n * NV + v) * Cc) * PLANE + (size_t)y * Ww + x;
    const float* fv = feats + (size_t)v * Cc * PLANE;
    if (winner >= 0) {
        #pragma unroll 8
        for (int c = 0; c < Cc; ++c) ob[(size_t)c * PLANE] = fv[(size_t)c * PLANE + winner];
    } else {
        #pragma unroll 8
        for (int c = 0; c < Cc; ++c) ob[(size_t)c * PLANE] = 0.0f;
    }
}

extern "C" void kernel_launch(void* const* d_in, const int* in_sizes, int n_in,
                              void* d_out, int out_size, void* d_ws, size_t ws_size,
                              hipStream_t stream) {
    const float* feats = (const float*)d_in[0];
    const int*   depth = (const int*)d_in[1];
    const float* novel = (const float*)d_in[2];
    const float* vpos  = (const float*)d_in[3];
    float* out = (float*)d_out;

    const size_t tr_bytes = (size_t)NV * Cc * PLANE * sizeof(float);  // 128 MiB
    if (ws_size >= tr_bytes) {
        float* tr = (float*)d_ws;
        transpose_k<<<NV * (PLANE / 64), 256, 0, stream>>>(feats, tr);
        warp_v2<<<NN * NV * (Hh / 4), 256, 0, stream>>>(tr, depth, novel, vpos, out);
    } else {
        warp_fallback<<<NN * NV * Hh, 256, 0, stream>>>(feats, depth, novel, vpos, out);
    }
}